// Round 2
// baseline (477.757 us; speedup 1.0000x reference)
//
#include <hip/hip_runtime.h>

#define B_DIM 1024
#define T_DIM 512
#define D_IN 32
#define H 64
#define CT 32                 // timesteps per staged X chunk
#define NCHUNK (T_DIM / CT)   // 16

// ---------------------------------------------------------------------------
// Kernel 1: fold embed+ih GEMMs: W_comb = W_ih @ W_emb  [64][32]
//           cvec = W_ih @ b_emb + b_ih + b_hh           [64]
// ---------------------------------------------------------------------------
__global__ __launch_bounds__(1024) void prep_kernel(
    const float* __restrict__ W_emb,  // [H][D_IN]
    const float* __restrict__ b_emb,  // [H]
    const float* __restrict__ W_ih,   // [H][H]
    const float* __restrict__ b_ih,   // [H]
    const float* __restrict__ b_hh,   // [H]
    float* __restrict__ Wc,           // [H][D_IN]
    float* __restrict__ cvec)         // [H]
{
    const int tid = threadIdx.x;
    const int i  = tid >> 4;    // 0..63  output row
    const int dg = tid & 15;    // 0..15  handles d = dg and dg+16
    float s0 = 0.f, s1 = 0.f;
    #pragma unroll
    for (int j = 0; j < H; ++j) {
        const float w = W_ih[i * H + j];
        s0 += w * W_emb[j * D_IN + dg];
        s1 += w * W_emb[j * D_IN + dg + 16];
    }
    Wc[i * D_IN + dg]      = s0;
    Wc[i * D_IN + dg + 16] = s1;
    if (dg == 0) {
        float s = b_ih[i] + b_hh[i];
        #pragma unroll
        for (int j = 0; j < H; ++j) s += W_ih[i * H + j] * b_emb[j];
        cvec[i] = s;
    }
}

// ---------------------------------------------------------------------------
// Kernel 2: fused input-projection + RNN scan + output projection.
// One wave (64 lanes) per batch element; lane i owns hidden unit i.
// __launch_bounds__(64, 1): 1 wave/EU min -> full 512-VGPR budget so
// whh[64] + wc[32] stay register-resident (R1: VGPR=68 proved they didn't).
// ---------------------------------------------------------------------------
__global__ __launch_bounds__(64, 1) void rnn_kernel(
    const float* __restrict__ X,      // [B][T][D_IN]
    const float* __restrict__ W_hh,   // [H][H]
    const float* __restrict__ Wc,     // [H][D_IN]
    const float* __restrict__ cvec,   // [H]
    const float* __restrict__ W_out,  // [1][H]
    const float* __restrict__ b_out,  // [1]
    float* __restrict__ out)          // [B]
{
    __shared__ __align__(16) float xs[2][CT * D_IN];  // 2 x 4 KB staged X
    __shared__ __align__(16) float hs[H];             // hidden state

    const int b = blockIdx.x;
    const int i = threadIdx.x;        // lane 0..63

    // --- per-lane weights into registers (row i of W_hh, row i of Wc) ---
    float whh[H];
    #pragma unroll
    for (int j = 0; j < H; j += 4) {
        const float4 v = *(const float4*)&W_hh[i * H + j];
        whh[j] = v.x; whh[j + 1] = v.y; whh[j + 2] = v.z; whh[j + 3] = v.w;
    }
    float wc[D_IN];
    #pragma unroll
    for (int d = 0; d < D_IN; d += 4) {
        const float4 v = *(const float4*)&Wc[i * D_IN + d];
        wc[d] = v.x; wc[d + 1] = v.y; wc[d + 2] = v.z; wc[d + 3] = v.w;
    }
    const float ci = cvec[i];

    const float* __restrict__ xb = X + (size_t)b * T_DIM * D_IN;

    // --- stage chunk 0 (CT*D_IN = 1024 floats; 4 float4 per lane) ---
    {
        float4 st[4];
        #pragma unroll
        for (int k = 0; k < 4; ++k) st[k] = *(const float4*)&xb[k * 256 + i * 4];
        #pragma unroll
        for (int k = 0; k < 4; ++k) *(float4*)&xs[0][k * 256 + i * 4] = st[k];
    }
    hs[i] = 0.f;
    float hlast = 0.f;

    #pragma unroll 1
    for (int c = 0; c < NCHUNK; ++c) {
        const int cur = c & 1;
        // prefetch next chunk into registers (HBM latency hides under compute)
        float4 pf[4];
        if (c + 1 < NCHUNK) {
            #pragma unroll
            for (int k = 0; k < 4; ++k)
                pf[k] = *(const float4*)&xb[(c + 1) * (CT * D_IN) + k * 256 + i * 4];
        }

        #pragma unroll 2
        for (int tt = 0; tt < CT; ++tt) {
            const float* __restrict__ xrow = &xs[cur][tt * D_IN];

            // pull h (broadcast) and x-row into registers; x-FMAs fill the
            // hv-read latency window (they don't depend on h).
            float hr[H];
            #pragma unroll
            for (int j = 0; j < H; j += 4)
                *(float4*)&hr[j] = *(const float4*)&hs[j];     // wave-broadcast
            float xr[D_IN];
            #pragma unroll
            for (int d = 0; d < D_IN; d += 4)
                *(float4*)&xr[d] = *(const float4*)&xrow[d];   // wave-broadcast

            // 8-way split accumulators: dep chain 12 deep instead of 24
            float a0 = ci,  a1 = 0.f, a2 = 0.f, a3 = 0.f;
            float a4 = 0.f, a5 = 0.f, a6 = 0.f, a7 = 0.f;
            #pragma unroll
            for (int d = 0; d < D_IN; d += 8) {
                a0 += wc[d]     * xr[d];
                a1 += wc[d + 1] * xr[d + 1];
                a2 += wc[d + 2] * xr[d + 2];
                a3 += wc[d + 3] * xr[d + 3];
                a4 += wc[d + 4] * xr[d + 4];
                a5 += wc[d + 5] * xr[d + 5];
                a6 += wc[d + 6] * xr[d + 6];
                a7 += wc[d + 7] * xr[d + 7];
            }
            #pragma unroll
            for (int j = 0; j < H; j += 8) {
                a0 += whh[j]     * hr[j];
                a1 += whh[j + 1] * hr[j + 1];
                a2 += whh[j + 2] * hr[j + 2];
                a3 += whh[j + 3] * hr[j + 3];
                a4 += whh[j + 4] * hr[j + 4];
                a5 += whh[j + 5] * hr[j + 5];
                a6 += whh[j + 6] * hr[j + 6];
                a7 += whh[j + 7] * hr[j + 7];
            }
            const float acc = ((a0 + a1) + (a2 + a3)) + ((a4 + a5) + (a6 + a7));
            // tanh(x) = 1 - 2/(exp(2x)+1); saturates correctly at +/-inf
            const float e  = __builtin_amdgcn_exp2f(acc * 2.885390081777927f); // 2*log2(e)
            const float hn = __builtin_fmaf(-2.f, __builtin_amdgcn_rcpf(e + 1.f), 1.f);
            hs[i] = hn;               // single wave: DS pipe is in-order
            hlast = hn;
        }

        // store prefetched chunk into the other buffer
        if (c + 1 < NCHUNK) {
            const int nxt = cur ^ 1;
            #pragma unroll
            for (int k = 0; k < 4; ++k)
                *(float4*)&xs[nxt][k * 256 + i * 4] = pf[k];
        }
    }

    // --- output projection: out[b] = dot(hT, W_out) + b_out ---
    float val = hlast * W_out[i];
    #pragma unroll
    for (int off = 32; off > 0; off >>= 1)
        val += __shfl_xor(val, off, 64);
    if (i == 0) out[b] = val + b_out[0];
}

// ---------------------------------------------------------------------------
extern "C" void kernel_launch(void* const* d_in, const int* in_sizes, int n_in,
                              void* d_out, int out_size, void* d_ws, size_t ws_size,
                              hipStream_t stream) {
    const float* X     = (const float*)d_in[0];
    const float* W_emb = (const float*)d_in[1];
    const float* b_emb = (const float*)d_in[2];
    const float* W_ih  = (const float*)d_in[3];
    const float* b_ih  = (const float*)d_in[4];
    const float* W_hh  = (const float*)d_in[5];
    const float* b_hh  = (const float*)d_in[6];
    const float* W_out = (const float*)d_in[7];
    const float* b_out = (const float*)d_in[8];
    float* out = (float*)d_out;

    float* Wc   = (float*)d_ws;                 // 64*32 floats = 8 KB
    float* cvec = (float*)d_ws + H * D_IN;      // 64 floats

    prep_kernel<<<1, 1024, 0, stream>>>(W_emb, b_emb, W_ih, b_ih, b_hh, Wc, cvec);
    rnn_kernel<<<B_DIM, 64, 0, stream>>>(X, W_hh, Wc, cvec, W_out, b_out, out);
}

// Round 3
// 290.049 us; speedup vs baseline: 1.6472x; 1.6472x over previous
//
#include <hip/hip_runtime.h>

#define B_DIM 1024
#define T_DIM 512
#define D_IN 32
#define H 64
#define CT 32                 // timesteps per staged X chunk
#define NCHUNK (T_DIM / CT)   // 16

// ---------------------------------------------------------------------------
// Kernel 1: fold embed+ih GEMMs: W_comb = W_ih @ W_emb  [64][32]
//           cvec = W_ih @ b_emb + b_ih + b_hh           [64]
// ---------------------------------------------------------------------------
__global__ __launch_bounds__(1024) void prep_kernel(
    const float* __restrict__ W_emb,  // [H][D_IN]
    const float* __restrict__ b_emb,  // [H]
    const float* __restrict__ W_ih,   // [H][H]
    const float* __restrict__ b_ih,   // [H]
    const float* __restrict__ b_hh,   // [H]
    float* __restrict__ Wc,           // [H][D_IN]
    float* __restrict__ cvec)         // [H]
{
    const int tid = threadIdx.x;
    const int i  = tid >> 4;    // 0..63  output row
    const int dg = tid & 15;    // 0..15  handles d = dg and dg+16
    float s0 = 0.f, s1 = 0.f;
    #pragma unroll
    for (int j = 0; j < H; ++j) {
        const float w = W_ih[i * H + j];
        s0 += w * W_emb[j * D_IN + dg];
        s1 += w * W_emb[j * D_IN + dg + 16];
    }
    Wc[i * D_IN + dg]      = s0;
    Wc[i * D_IN + dg + 16] = s1;
    if (dg == 0) {
        float s = b_ih[i] + b_hh[i];
        #pragma unroll
        for (int j = 0; j < H; ++j) s += W_ih[i * H + j] * b_emb[j];
        cvec[i] = s;
    }
}

// ---------------------------------------------------------------------------
// Kernel 2: fused input-projection + RNN scan + output projection.
// One wave (64 lanes) per batch element; lane i owns hidden unit i.
// amdgpu_waves_per_eu(1,1): occupancy is structurally 1 wave/SIMD (1024
// blocks / 256 CU = 4 waves/CU), so tell regalloc that reducing VGPRs buys
// nothing. asm pins stop the scheduler rematerializing weight loads into
// the serial loop (R1: VGPR=68, R2: VGPR=64 proved it does that).
// ---------------------------------------------------------------------------
__global__ __attribute__((amdgpu_flat_work_group_size(64, 64),
                          amdgpu_waves_per_eu(1, 1)))
void rnn_kernel(
    const float* __restrict__ X,      // [B][T][D_IN]
    const float* __restrict__ W_hh,   // [H][H]
    const float* __restrict__ Wc,     // [H][D_IN]
    const float* __restrict__ cvec,   // [H]
    const float* __restrict__ W_out,  // [1][H]
    const float* __restrict__ b_out,  // [1]
    float* __restrict__ out)          // [B]
{
    __shared__ __align__(16) float xs[2][CT * D_IN];  // 2 x 4 KB staged X
    __shared__ __align__(16) float hs[H];             // hidden state

    const int b = blockIdx.x;
    const int i = threadIdx.x;        // lane 0..63

    // --- per-lane weights into registers (row i of W_hh, row i of Wc) ---
    float whh[H];
    #pragma unroll
    for (int j = 0; j < H; j += 4) {
        const float4 v = *(const float4*)&W_hh[i * H + j];
        whh[j] = v.x; whh[j + 1] = v.y; whh[j + 2] = v.z; whh[j + 3] = v.w;
    }
    float wc[D_IN];
    #pragma unroll
    for (int d = 0; d < D_IN; d += 4) {
        const float4 v = *(const float4*)&Wc[i * D_IN + d];
        wc[d] = v.x; wc[d + 1] = v.y; wc[d + 2] = v.z; wc[d + 3] = v.w;
    }
    float ci = cvec[i];

    // Pin every weight in a VGPR: opaque to the optimizer, so the loads
    // cannot be rematerialized/sunk into the timestep loop.
    #pragma unroll
    for (int j = 0; j < H; ++j) asm volatile("" : "+v"(whh[j]));
    #pragma unroll
    for (int d = 0; d < D_IN; ++d) asm volatile("" : "+v"(wc[d]));
    asm volatile("" : "+v"(ci));

    const float* __restrict__ xb = X + (size_t)b * T_DIM * D_IN;

    // --- stage chunk 0 (CT*D_IN = 1024 floats; 4 float4 per lane) ---
    {
        float4 st[4];
        #pragma unroll
        for (int k = 0; k < 4; ++k) st[k] = *(const float4*)&xb[k * 256 + i * 4];
        #pragma unroll
        for (int k = 0; k < 4; ++k) *(float4*)&xs[0][k * 256 + i * 4] = st[k];
    }
    hs[i] = 0.f;
    float hlast = 0.f;

    #pragma unroll 1
    for (int c = 0; c < NCHUNK; ++c) {
        const int cur = c & 1;
        // prefetch next chunk into registers (HBM latency hides under compute)
        float4 pf[4];
        if (c + 1 < NCHUNK) {
            #pragma unroll
            for (int k = 0; k < 4; ++k)
                pf[k] = *(const float4*)&xb[(c + 1) * (CT * D_IN) + k * 256 + i * 4];
        }

        #pragma unroll 4
        for (int tt = 0; tt < CT; ++tt) {
            const float* __restrict__ xrow = &xs[cur][tt * D_IN];

            // Issue x reads FIRST, h reads second: the x-FMAs then run while
            // the h reads are still in flight (they only need lgkmcnt(16)),
            // hiding LDS latency inside the serial step.
            float4 xv[8];
            #pragma unroll
            for (int d = 0; d < 8; ++d) xv[d] = *(const float4*)&xrow[d * 4];
            float4 hv[16];
            #pragma unroll
            for (int j = 0; j < 16; ++j) hv[j] = *(const float4*)&hs[j * 4];

            // 8-way split accumulators: dep chain ~12 deep instead of 24
            float a0 = ci,  a1 = 0.f, a2 = 0.f, a3 = 0.f;
            float a4 = 0.f, a5 = 0.f, a6 = 0.f, a7 = 0.f;
            #pragma unroll
            for (int d = 0; d < 8; d += 2) {
                a0 += wc[d * 4 + 0] * xv[d].x;
                a1 += wc[d * 4 + 1] * xv[d].y;
                a2 += wc[d * 4 + 2] * xv[d].z;
                a3 += wc[d * 4 + 3] * xv[d].w;
                a4 += wc[d * 4 + 4] * xv[d + 1].x;
                a5 += wc[d * 4 + 5] * xv[d + 1].y;
                a6 += wc[d * 4 + 6] * xv[d + 1].z;
                a7 += wc[d * 4 + 7] * xv[d + 1].w;
            }
            #pragma unroll
            for (int j = 0; j < 16; j += 2) {
                a0 += whh[j * 4 + 0] * hv[j].x;
                a1 += whh[j * 4 + 1] * hv[j].y;
                a2 += whh[j * 4 + 2] * hv[j].z;
                a3 += whh[j * 4 + 3] * hv[j].w;
                a4 += whh[j * 4 + 4] * hv[j + 1].x;
                a5 += whh[j * 4 + 5] * hv[j + 1].y;
                a6 += whh[j * 4 + 6] * hv[j + 1].z;
                a7 += whh[j * 4 + 7] * hv[j + 1].w;
            }
            const float acc = ((a0 + a1) + (a2 + a3)) + ((a4 + a5) + (a6 + a7));
            // tanh(x) = 1 - 2/(exp(2x)+1); saturates correctly at +/-inf
            const float e  = __builtin_amdgcn_exp2f(acc * 2.885390081777927f); // 2*log2(e)
            const float hn = __builtin_fmaf(-2.f, __builtin_amdgcn_rcpf(e + 1.f), 1.f);
            hs[i] = hn;               // single wave: DS pipe is in-order
            hlast = hn;
        }

        // store prefetched chunk into the other buffer
        if (c + 1 < NCHUNK) {
            const int nxt = cur ^ 1;
            #pragma unroll
            for (int k = 0; k < 4; ++k)
                *(float4*)&xs[nxt][k * 256 + i * 4] = pf[k];
        }
    }

    // --- output projection: out[b] = dot(hT, W_out) + b_out ---
    float val = hlast * W_out[i];
    #pragma unroll
    for (int off = 32; off > 0; off >>= 1)
        val += __shfl_xor(val, off, 64);
    if (i == 0) out[b] = val + b_out[0];
}

// ---------------------------------------------------------------------------
extern "C" void kernel_launch(void* const* d_in, const int* in_sizes, int n_in,
                              void* d_out, int out_size, void* d_ws, size_t ws_size,
                              hipStream_t stream) {
    const float* X     = (const float*)d_in[0];
    const float* W_emb = (const float*)d_in[1];
    const float* b_emb = (const float*)d_in[2];
    const float* W_ih  = (const float*)d_in[3];
    const float* b_ih  = (const float*)d_in[4];
    const float* W_hh  = (const float*)d_in[5];
    const float* b_hh  = (const float*)d_in[6];
    const float* W_out = (const float*)d_in[7];
    const float* b_out = (const float*)d_in[8];
    float* out = (float*)d_out;

    float* Wc   = (float*)d_ws;                 // 64*32 floats = 8 KB
    float* cvec = (float*)d_ws + H * D_IN;      // 64 floats

    prep_kernel<<<1, 1024, 0, stream>>>(W_emb, b_emb, W_ih, b_ih, b_hh, Wc, cvec);
    rnn_kernel<<<B_DIM, 64, 0, stream>>>(X, W_hh, Wc, cvec, W_out, b_out, out);
}

// Round 5
// 283.627 us; speedup vs baseline: 1.6845x; 1.0226x over previous
//
#include <hip/hip_runtime.h>

#define B_DIM 1024
#define T_DIM 512
#define D_IN 32
#define H 64
#define CT 32                 // timesteps per staged X chunk
#define NCHUNK (T_DIM / CT)   // 16

// ---------------------------------------------------------------------------
// Single fused kernel. One wave (64 lanes) per batch element; lane i owns
// hidden unit i. h lives in ONE VGPR per lane; the recurrent matvec pulls
// h[j] via v_readlane (SGPR broadcast) -> no LDS round-trip on the serial
// chain (R3: 992 cyc/step, half of it LDS waits + register-copy junk).
// Each block folds W_comb = W_ih@W_emb itself (~2us, parallel), removing
// the prep dispatch + inter-kernel gap (~80us in R1-R3).
// ---------------------------------------------------------------------------
__global__ __attribute__((amdgpu_flat_work_group_size(64, 64),
                          amdgpu_waves_per_eu(1, 1)))
void rnn_kernel(
    const float* __restrict__ X,      // [B][T][D_IN]
    const float* __restrict__ W_emb,  // [H][D_IN]
    const float* __restrict__ b_emb,  // [H]
    const float* __restrict__ W_ih,   // [H][H]
    const float* __restrict__ b_ih,   // [H]
    const float* __restrict__ W_hh,   // [H][H]
    const float* __restrict__ b_hh,   // [H]
    const float* __restrict__ W_out,  // [1][H]
    const float* __restrict__ b_out,  // [1]
    float* __restrict__ out)          // [B]
{
    __shared__ __align__(16) float wemb[H * D_IN];    // 8 KB (prep only)
    __shared__ __align__(16) float bemb[H];
    __shared__ __align__(16) float xs[2][CT * D_IN];  // 8 KB staged X

    const int b = blockIdx.x;
    const int i = threadIdx.x;        // lane 0..63

    const float* __restrict__ xb = X + (size_t)b * T_DIM * D_IN;

    // ---- kick off X chunk-0 global loads early (latency hides under prep) --
    float4 st0, st1, st2, st3;
    st0 = *(const float4*)&xb[0 * 256 + i * 4];
    st1 = *(const float4*)&xb[1 * 256 + i * 4];
    st2 = *(const float4*)&xb[2 * 256 + i * 4];
    st3 = *(const float4*)&xb[3 * 256 + i * 4];

    // ---- stage W_emb + b_emb into LDS (coalesced) ----
    #pragma unroll
    for (int k = 0; k < 8; ++k)
        *(float4*)&wemb[k * 256 + i * 4] = *(const float4*)&W_emb[k * 256 + i * 4];
    bemb[i] = b_emb[i];

    // ---- W_ih row i into registers ----
    float wih[H];
    #pragma unroll
    for (int j = 0; j < H; j += 4) {
        const float4 v = *(const float4*)&W_ih[i * H + j];
        wih[j] = v.x; wih[j + 1] = v.y; wih[j + 2] = v.z; wih[j + 3] = v.w;
    }

    // ---- fold: wc[d] = sum_j wih[j]*W_emb[j][d];  ci = b_ih+b_hh+sum wih[j]*b_emb[j]
    float wc[D_IN];
    #pragma unroll
    for (int d = 0; d < D_IN; ++d) wc[d] = 0.f;
    float ci = b_ih[i] + b_hh[i];
    #pragma unroll 4
    for (int j = 0; j < H; ++j) {           // LDS reads are wave-broadcast
        const float wj = wih[j];
        ci += wj * bemb[j];
        #pragma unroll
        for (int d = 0; d < D_IN; d += 4) {
            const float4 e = *(const float4*)&wemb[j * D_IN + d];
            wc[d]     += wj * e.x;
            wc[d + 1] += wj * e.y;
            wc[d + 2] += wj * e.z;
            wc[d + 3] += wj * e.w;
        }
    }

    // ---- W_hh row i into registers (wih now dead) ----
    float whh[H];
    #pragma unroll
    for (int j = 0; j < H; j += 4) {
        const float4 v = *(const float4*)&W_hh[i * H + j];
        whh[j] = v.x; whh[j + 1] = v.y; whh[j + 2] = v.z; whh[j + 3] = v.w;
    }

    // Pin loop-invariants into VGPRs (R3: this got weights resident).
    #pragma unroll
    for (int j = 0; j < H; ++j) asm volatile("" : "+v"(whh[j]));
    #pragma unroll
    for (int d = 0; d < D_IN; ++d) asm volatile("" : "+v"(wc[d]));
    asm volatile("" : "+v"(ci));

    // ---- write chunk 0 into LDS ----
    *(float4*)&xs[0][0 * 256 + i * 4] = st0;
    *(float4*)&xs[0][1 * 256 + i * 4] = st1;
    *(float4*)&xs[0][2 * 256 + i * 4] = st2;
    *(float4*)&xs[0][3 * 256 + i * 4] = st3;

    float h = 0.f;                    // lane i holds h[i]

    #pragma unroll 1
    for (int c = 0; c < NCHUNK; ++c) {
        const int cur = c & 1;
        // prefetch next chunk into registers
        float4 pf0, pf1, pf2, pf3;
        if (c + 1 < NCHUNK) {
            const float* __restrict__ nb = &xb[(c + 1) * (CT * D_IN)];
            pf0 = *(const float4*)&nb[0 * 256 + i * 4];
            pf1 = *(const float4*)&nb[1 * 256 + i * 4];
            pf2 = *(const float4*)&nb[2 * 256 + i * 4];
            pf3 = *(const float4*)&nb[3 * 256 + i * 4];
        }

        #pragma unroll 2
        for (int tt = 0; tt < CT; ++tt) {
            const float* __restrict__ xrow = &xs[cur][tt * D_IN];

            // Issue x reads first (DS pipe; latency overlaps the readlane
            // stream below, which has no LDS dependency).
            const float4 x0 = *(const float4*)&xrow[0];
            const float4 x1 = *(const float4*)&xrow[4];
            const float4 x2 = *(const float4*)&xrow[8];
            const float4 x3 = *(const float4*)&xrow[12];
            const float4 x4 = *(const float4*)&xrow[16];
            const float4 x5 = *(const float4*)&xrow[20];
            const float4 x6 = *(const float4*)&xrow[24];
            const float4 x7 = *(const float4*)&xrow[28];

            float a[8];
            a[0] = ci;
            #pragma unroll
            for (int k = 1; k < 8; ++k) a[k] = 0.f;

            // --- recurrent matvec: h[j] via readlane (no memory) ---
            const int hb = __float_as_int(h);
            #pragma unroll
            for (int j = 0; j < H; ++j) {
                const float hj = __int_as_float(__builtin_amdgcn_readlane(hb, j));
                a[j & 7] += whh[j] * hj;
            }

            // --- input projection FMAs (reads landed long ago) ---
            a[0] += wc[0]  * x0.x;  a[1] += wc[1]  * x0.y;
            a[2] += wc[2]  * x0.z;  a[3] += wc[3]  * x0.w;
            a[4] += wc[4]  * x1.x;  a[5] += wc[5]  * x1.y;
            a[6] += wc[6]  * x1.z;  a[7] += wc[7]  * x1.w;
            a[0] += wc[8]  * x2.x;  a[1] += wc[9]  * x2.y;
            a[2] += wc[10] * x2.z;  a[3] += wc[11] * x2.w;
            a[4] += wc[12] * x3.x;  a[5] += wc[13] * x3.y;
            a[6] += wc[14] * x3.z;  a[7] += wc[15] * x3.w;
            a[0] += wc[16] * x4.x;  a[1] += wc[17] * x4.y;
            a[2] += wc[18] * x4.z;  a[3] += wc[19] * x4.w;
            a[4] += wc[20] * x5.x;  a[5] += wc[21] * x5.y;
            a[6] += wc[22] * x5.z;  a[7] += wc[23] * x5.w;
            a[0] += wc[24] * x6.x;  a[1] += wc[25] * x6.y;
            a[2] += wc[26] * x6.z;  a[3] += wc[27] * x6.w;
            a[4] += wc[28] * x7.x;  a[5] += wc[29] * x7.y;
            a[6] += wc[30] * x7.z;  a[7] += wc[31] * x7.w;

            const float acc = ((a[0] + a[1]) + (a[2] + a[3]))
                            + ((a[4] + a[5]) + (a[6] + a[7]));
            // tanh(x) = 1 - 2/(exp(2x)+1); saturates correctly at +/-inf
            const float e  = __builtin_amdgcn_exp2f(acc * 2.885390081777927f);
            h = __builtin_fmaf(-2.f, __builtin_amdgcn_rcpf(e + 1.f), 1.f);
        }

        // store prefetched chunk into the other buffer (single wave: program
        // order + lgkmcnt keeps write/read of xs correctly ordered)
        if (c + 1 < NCHUNK) {
            const int nxt = cur ^ 1;
            *(float4*)&xs[nxt][0 * 256 + i * 4] = pf0;
            *(float4*)&xs[nxt][1 * 256 + i * 4] = pf1;
            *(float4*)&xs[nxt][2 * 256 + i * 4] = pf2;
            *(float4*)&xs[nxt][3 * 256 + i * 4] = pf3;
        }
    }

    // --- output projection: out[b] = dot(hT, W_out) + b_out ---
    float val = h * W_out[i];
    #pragma unroll
    for (int off = 32; off > 0; off >>= 1)
        val += __shfl_xor(val, off, 64);
    if (i == 0) out[b] = val + b_out[0];
}

// ---------------------------------------------------------------------------
extern "C" void kernel_launch(void* const* d_in, const int* in_sizes, int n_in,
                              void* d_out, int out_size, void* d_ws, size_t ws_size,
                              hipStream_t stream) {
    const float* X     = (const float*)d_in[0];
    const float* W_emb = (const float*)d_in[1];
    const float* b_emb = (const float*)d_in[2];
    const float* W_ih  = (const float*)d_in[3];
    const float* b_ih  = (const float*)d_in[4];
    const float* W_hh  = (const float*)d_in[5];
    const float* b_hh  = (const float*)d_in[6];
    const float* W_out = (const float*)d_in[7];
    const float* b_out = (const float*)d_in[8];
    float* out = (float*)d_out;

    rnn_kernel<<<B_DIM, 64, 0, stream>>>(X, W_emb, b_emb, W_ih, b_ih,
                                         W_hh, b_hh, W_out, b_out, out);
}